// Round 5
// baseline (120.184 us; speedup 1.0000x reference)
//
#include <hip/hip_runtime.h>
#include <hip/hip_bf16.h>
#include <cstdint>
#include <cmath>

#define BB 4
#define TT 2048
#define DD 512
#define RR 1024
#define MM (BB*RR)       // 4096
#define NBINS 13
#define LDXP (NBINS*DD)  // 6656

typedef __bf16 bf16;
typedef bf16 bf16x8 __attribute__((ext_vector_type(8)));
typedef bf16 bf16x2 __attribute__((ext_vector_type(2)));
typedef float f32x4 __attribute__((ext_vector_type(4)));

__device__ __forceinline__ float selu_f(float x) {
    const float sc = 1.0507009873554805f;
    const float aa = 1.6732632423543772f;
    return x > 0.0f ? sc * x : sc * aa * (expf(x) - 1.0f);
}

__device__ __forceinline__ void gload_lds16(const bf16* g, bf16* l) {
    __builtin_amdgcn_global_load_lds(
        (const __attribute__((address_space(1))) void*)g,
        (__attribute__((address_space(3))) void*)l, 16, 0, 0);
}

__device__ __forceinline__ void waitb() {
    asm volatile("s_waitcnt vmcnt(0)" ::: "memory");
    __builtin_amdgcn_s_barrier();
}

// Stage a [ROWS][64] bf16 tile into LDS, XOR-swizzled: physical 16B slot p of
// row r holds logical slot p ^ (r&7).  LDS dest stays linear (global_load_lds
// writes wave-base + lane*16); the source address carries the permutation.
template<int ROWS>
__device__ __forceinline__ void stage_tile64(const bf16* __restrict__ src, int lda,
                                             bf16* tile, int tid) {
#pragma unroll
    for (int it = 0; it < ROWS / 32; ++it) {     // 256 threads cover 32 rows/iter
        int idx = it * 256 + tid;
        int row = idx >> 3;                       // 8 slots of 16B per 128B row
        int col = ((idx & 7) ^ (row & 7)) * 8;
        bf16* wavebase = tile + (idx & ~63) * 8;  // wave-uniform base
        gload_lds16(src + (size_t)row * lda + col, wavebase);
    }
}

// Fragment read with the matching XOR: logical slot s of row r lives at
// physical slot s ^ (r&7).  16 lanes (rows r..r+15) spread over 8 slots -> 2-way.
__device__ __forceinline__ bf16x8 frd64(const bf16* tile, int row, int s) {
    int p = s ^ (row & 7);
    return *(const bf16x8*)(tile + row * 64 + p * 8);
}

// ---------------- fused prep: pool + weight transforms ----------------
// Weight interleave as LDS-staged transpose: coalesced read AND write.
// Wdst[n][bin*512+d] = Wsrc[n][d*NB_+bin]
template<int NB_, int KT>
__device__ __forceinline__ void w_row_body(const float* __restrict__ Wsrc,
                                           bf16* __restrict__ Wdst,
                                           float* ld, int n, int tid) {
    const float* src = Wsrc + (size_t)n * KT;
    for (int i = tid; i < KT; i += 256) ld[i] = src[i];
    __syncthreads();
    bf16* dst = Wdst + (size_t)n * KT;
    for (int i = tid; i < KT; i += 256) {
        int bin = i >> 9, d = i & 511;
        dst[i] = (bf16)ld[d * NB_ + bin];
    }
}

__device__ __forceinline__ void pool_body(const float* __restrict__ feats,
                                          const float* __restrict__ rois,
                                          bf16* __restrict__ Xp, int m, int tid) {
    int b = m >> 10;
    float s = rois[2 * m];
    float e = rois[2 * m + 1];
    float ext = 0.2f * (e - s);
    int d0 = tid * 2;
    bf16* orow = Xp + (size_t)m * LDXP + d0;
    const float* fb = feats + (size_t)b * TT * DD + d0;
#pragma unroll
    for (int j = 0; j < NBINS; ++j) {
        float pos;
        if (j < 2)       pos = (s - ext) + ((float)j + 0.5f) * ext;
        else if (j < 11) pos = s + (((float)(j - 2) + 0.5f) * (1.0f / 9.0f)) * (e - s);
        else             pos = (e - ext) + ((float)(j - 11) + 0.5f) * ext;
        pos = fminf(fmaxf(pos, 0.0f), (float)(TT - 1));
        float fl = floorf(pos);
        int lo = (int)fl;
        int hi = lo + 1; if (hi > TT - 1) hi = TT - 1;
        float w = pos - fl;
        float2 vlo = *(const float2*)(fb + (size_t)lo * DD);
        float2 vhi = *(const float2*)(fb + (size_t)hi * DD);
        bf16x2 o;
        o.x = (bf16)((1.0f - w) * vlo.x + w * vhi.x);
        o.y = (bf16)((1.0f - w) * vlo.y + w * vhi.y);
        *(bf16x2*)(orow + j * DD) = o;
    }
}

// blocks 0..4095: pool | 4096..4607: Wl rows | 4608..5119: Wi rows | 5120..5631: Wr
__global__ __launch_bounds__(256) void prep_all(
    const float* __restrict__ feats, const float* __restrict__ rois,
    const float* __restrict__ W_left, const float* __restrict__ W_inner,
    const float* __restrict__ W_roi,
    bf16* __restrict__ Xp, bf16* __restrict__ Wl, bf16* __restrict__ Wi,
    bf16* __restrict__ Wr)
{
    __shared__ float ld[4608];
    int bid = blockIdx.x, tid = threadIdx.x;
    if (bid < 4096) {
        pool_body(feats, rois, Xp, bid, tid);
    } else if (bid < 4608) {
        w_row_body<7, 3584>(W_left, Wl, ld, bid - 4096, tid);
    } else if (bid < 5120) {
        w_row_body<9, 4608>(W_inner, Wi, ld, bid - 4608, tid);
    } else {
        int i0 = (bid - 5120) * 1024 + tid * 4;
        float4 v = *(const float4*)(W_roi + i0);
        bf16* d = Wr + i0;
        d[0] = (bf16)v.x; d[1] = (bf16)v.y; d[2] = (bf16)v.z; d[3] = (bf16)v.w;
    }
}

// ---------------- GEMM bodies ----------------
// BM=64, BN=128, BK=64; 256 threads = 4 waves (2x2), wave tile 32x64 (2x4 frags).
// r3 schedule: double-buffered LDS, prefetch issued before compute, one
// vmcnt(0)+s_barrier per K-step, setprio around the MFMA cluster.

template<int K, bool OUT_BF16>
__device__ __forceinline__ void gemm_single_body(
    const bf16* __restrict__ A, int lda,
    const bf16* __restrict__ Bw, const float* __restrict__ bias,
    void* __restrict__ Out, int ldo, int ocol0,
    bf16* sm, int m0, int n0)
{
    int tid = threadIdx.x, lane = tid & 63, w = tid >> 6;
    int wr = w >> 1, wc = w & 1;
    const bf16* Ab = A + (size_t)m0 * lda;
    const bf16* Bb = Bw + (size_t)n0 * K;
    int frow = lane & 15, sl = lane >> 4;
    f32x4 acc[2][4] = {};
    bf16 *A0 = sm,         *B0 = sm + 4096;
    bf16 *A1 = sm + 12288, *B1 = sm + 12288 + 4096;

    auto stage = [&](bf16* as, bf16* bs, int t) {
        stage_tile64<64>(Ab + t * 64, lda, as, tid);
        stage_tile64<128>(Bb + t * 64, K, bs, tid);
    };
    auto compute = [&](const bf16* as, const bf16* bs) {
#pragma unroll
        for (int ks = 0; ks < 2; ++ks) {
            bf16x8 af[2], bfr[4];
#pragma unroll
            for (int mf = 0; mf < 2; ++mf) af[mf] = frd64(as, wr * 32 + mf * 16 + frow, ks * 4 + sl);
#pragma unroll
            for (int nf = 0; nf < 4; ++nf) bfr[nf] = frd64(bs, wc * 64 + nf * 16 + frow, ks * 4 + sl);
            __builtin_amdgcn_s_setprio(1);
#pragma unroll
            for (int mf = 0; mf < 2; ++mf)
#pragma unroll
                for (int nf = 0; nf < 4; ++nf)
                    acc[mf][nf] = __builtin_amdgcn_mfma_f32_16x16x32_bf16(af[mf], bfr[nf], acc[mf][nf], 0, 0, 0);
            __builtin_amdgcn_s_setprio(0);
        }
    };

    constexpr int NT = K / 64;   // even for all instantiations
    stage(A0, B0, 0);
    waitb();
    for (int t = 0; t < NT; t += 2) {
        stage(A1, B1, t + 1);
        compute(A0, B0);
        waitb();
        if (t + 2 < NT) stage(A0, B0, t + 2);
        compute(A1, B1);
        waitb();
    }
    int crow = (lane >> 4) * 4;
    int ccol = lane & 15;
#pragma unroll
    for (int mf = 0; mf < 2; ++mf) {
#pragma unroll
        for (int nf = 0; nf < 4; ++nf) {
            int col = n0 + wc * 64 + nf * 16 + ccol;
            float bv = bias[col];
#pragma unroll
            for (int r2 = 0; r2 < 4; ++r2) {
                int row = m0 + wr * 32 + mf * 16 + crow + r2;
                float v = selu_f(acc[mf][nf][r2] + bv);
                if constexpr (OUT_BF16)
                    ((bf16*)Out)[(size_t)row * ldo + ocol0 + col] = (bf16)v;
                else
                    ((float*)Out)[(size_t)row * ldo + ocol0 + col] = v;
            }
        }
    }
}

template<int K>
__device__ __forceinline__ void gemm_dual_body(
    const bf16* __restrict__ Xp, const bf16* __restrict__ Wl,
    const float* __restrict__ bias, bf16* __restrict__ Y,
    bf16* sm, int m0, int n0)
{
    int tid = threadIdx.x, lane = tid & 63, w = tid >> 6;
    int wr = w >> 1, wc = w & 1;
    const bf16* AL = Xp + (size_t)m0 * LDXP;         // bins 0..6
    const bf16* AR = AL + 3072;                      // bins 6..12
    const bf16* Bb = Wl + (size_t)n0 * K;
    int frow = lane & 15, sl = lane >> 4;
    f32x4 accL[2][4] = {}, accR[2][4] = {};
    bf16 *L0 = sm,         *R0 = sm + 4096,         *B0 = sm + 8192;
    bf16 *L1 = sm + 16384, *R1 = sm + 16384 + 4096, *B1 = sm + 16384 + 8192;

    auto stage = [&](bf16* ls, bf16* rs, bf16* bs, int t) {
        stage_tile64<64>(AL + t * 64, LDXP, ls, tid);
        stage_tile64<64>(AR + t * 64, LDXP, rs, tid);
        stage_tile64<128>(Bb + t * 64, K, bs, tid);
    };
    auto compute = [&](const bf16* ls, const bf16* rs, const bf16* bs) {
#pragma unroll
        for (int ks = 0; ks < 2; ++ks) {
            bf16x8 afL[2], afR[2], bfr[4];
#pragma unroll
            for (int mf = 0; mf < 2; ++mf) {
                afL[mf] = frd64(ls, wr * 32 + mf * 16 + frow, ks * 4 + sl);
                afR[mf] = frd64(rs, wr * 32 + mf * 16 + frow, ks * 4 + sl);
            }
#pragma unroll
            for (int nf = 0; nf < 4; ++nf) bfr[nf] = frd64(bs, wc * 64 + nf * 16 + frow, ks * 4 + sl);
            __builtin_amdgcn_s_setprio(1);
#pragma unroll
            for (int mf = 0; mf < 2; ++mf)
#pragma unroll
                for (int nf = 0; nf < 4; ++nf) {
                    accL[mf][nf] = __builtin_amdgcn_mfma_f32_16x16x32_bf16(afL[mf], bfr[nf], accL[mf][nf], 0, 0, 0);
                    accR[mf][nf] = __builtin_amdgcn_mfma_f32_16x16x32_bf16(afR[mf], bfr[nf], accR[mf][nf], 0, 0, 0);
                }
            __builtin_amdgcn_s_setprio(0);
        }
    };

    constexpr int NT = K / 64;   // 56
    stage(L0, R0, B0, 0);
    waitb();
    for (int t = 0; t < NT; t += 2) {
        stage(L1, R1, B1, t + 1);
        compute(L0, R0, B0);
        waitb();
        if (t + 2 < NT) stage(L0, R0, B0, t + 2);
        compute(L1, R1, B1);
        waitb();
    }
    int crow = (lane >> 4) * 4;
    int ccol = lane & 15;
#pragma unroll
    for (int mf = 0; mf < 2; ++mf) {
#pragma unroll
        for (int nf = 0; nf < 4; ++nf) {
            int col = n0 + wc * 64 + nf * 16 + ccol;
            float bv = bias[col];
#pragma unroll
            for (int r2 = 0; r2 < 4; ++r2) {
                int row = m0 + wr * 32 + mf * 16 + crow + r2;
                float vL = selu_f(accL[mf][nf][r2] + bv);
                float vR = selu_f(accR[mf][nf][r2] + bv);
                Y[(size_t)row * 1024 + col] = (bf16)(vR - vL);
            }
        }
    }
}

// ---------------- GEMM kernels ----------------
// XCD-aware mapping: block b lands on XCD b%8.  Per XCD: 32 dual + 32 inner
// blocks, all sharing ONE n-strip (xcd&3) -> per-XCD weight footprint
// Wl_strip(0.92MB)+Wi_strip(1.18MB) = 2.1MB, L2-resident.  m-tiles are
// consecutive within an XCD for Xp L3 locality.
__global__ __launch_bounds__(256) void wide_gemm(
    const bf16* __restrict__ Xp, const bf16* __restrict__ Wl,
    const float* __restrict__ bl, const bf16* __restrict__ Wi,
    const float* __restrict__ bi, bf16* __restrict__ Y)
{
    __shared__ bf16 sm[32768];  // 64 KB: 2 x (64+64+128)x64
    int b = blockIdx.x;
    int xcd = b & 7, slot = b >> 3;          // slot 0..63
    int n0 = (xcd & 3) * 128;
    if (slot < 32) {
        int m0 = ((xcd >> 2) * 32 + slot) * 64;
        gemm_dual_body<3584>(Xp, Wl, bl, Y, sm, m0, n0);
    } else {
        int m0 = ((xcd >> 2) * 32 + (slot - 32)) * 64;
        gemm_single_body<4608, true>(Xp + 1024, LDXP, Wi, bi, (void*)Y, 1024, 512,
                                     sm, m0, n0);
    }
}

__global__ __launch_bounds__(256) void final_gemm(
    const bf16* __restrict__ Y, const bf16* __restrict__ Wr,
    const float* __restrict__ br, float* __restrict__ out)
{
    __shared__ bf16 sm[24576];  // 48 KB
    int b = blockIdx.x;
    int xcd = b & 7, slot = b >> 3;          // slot 0..31
    int n0 = (xcd & 3) * 128;
    int m0 = ((xcd >> 2) * 32 + slot) * 64;
    gemm_single_body<1024, false>(Y, 1024, Wr, br, (void*)out, 512, 0,
                                  sm, m0, n0);
}

// ---------------- launch ----------------
extern "C" void kernel_launch(void* const* d_in, const int* in_sizes, int n_in,
                              void* d_out, int out_size, void* d_ws, size_t ws_size,
                              hipStream_t stream) {
    const float* feats   = (const float*)d_in[0];
    const float* rois    = (const float*)d_in[3];
    const float* W_left  = (const float*)d_in[6];
    const float* b_left  = (const float*)d_in[7];
    const float* W_inner = (const float*)d_in[8];
    const float* b_inner = (const float*)d_in[9];
    const float* W_roi   = (const float*)d_in[10];
    const float* b_roi   = (const float*)d_in[11];
    float* out = (float*)d_out;

    bf16* wsb = (bf16*)d_ws;
    constexpr size_t XP_ELEMS = (size_t)MM * LDXP;
    constexpr size_t WL_ELEMS = (size_t)512 * 3584;
    constexpr size_t WI_ELEMS = (size_t)512 * 4608;
    constexpr size_t WR_ELEMS = (size_t)512 * 1024;
    bf16* Xp = wsb;
    bf16* Wl = Xp + XP_ELEMS;
    bf16* Wi = Wl + WL_ELEMS;
    bf16* Wr = Wi + WI_ELEMS;
    bf16* Y  = Wr + WR_ELEMS;   // [M][1024]

    prep_all<<<5632, 256, 0, stream>>>(feats, rois, W_left, W_inner, W_roi,
                                       Xp, Wl, Wi, Wr);
    wide_gemm<<<512, 256, 0, stream>>>(Xp, Wl, b_left, Wi, b_inner, Y);
    final_gemm<<<256, 256, 0, stream>>>(Y, Wr, b_roi, out);
}

// Round 6
// 103.962 us; speedup vs baseline: 1.1560x; 1.1560x over previous
//
#include <hip/hip_runtime.h>
#include <hip/hip_bf16.h>
#include <cstdint>
#include <cmath>

#define BB 4
#define TT 2048
#define DD 512
#define RR 1024
#define MM (BB*RR)       // 4096
#define NBINS 13
#define LDXP (NBINS*DD)  // 6656

typedef __bf16 bf16;
typedef bf16 bf16x8 __attribute__((ext_vector_type(8)));
typedef bf16 bf16x2 __attribute__((ext_vector_type(2)));
typedef float f32x4 __attribute__((ext_vector_type(4)));

__device__ __forceinline__ float selu_f(float x) {
    const float sc = 1.0507009873554805f;
    const float aa = 1.6732632423543772f;
    return x > 0.0f ? sc * x : sc * aa * (expf(x) - 1.0f);
}

__device__ __forceinline__ void gload_lds16(const bf16* g, bf16* l) {
    __builtin_amdgcn_global_load_lds(
        (const __attribute__((address_space(1))) void*)g,
        (__attribute__((address_space(3))) void*)l, 16, 0, 0);
}

template<int N>
__device__ __forceinline__ void wait_vm() {
    if constexpr (N == 0)      asm volatile("s_waitcnt vmcnt(0)" ::: "memory");
    else if constexpr (N == 6) asm volatile("s_waitcnt vmcnt(6)" ::: "memory");
    else if constexpr (N == 8) asm volatile("s_waitcnt vmcnt(8)" ::: "memory");
}

// Stage a [ROWS][64] bf16 tile into LDS, XOR-swizzled: physical 16B slot p of
// row r holds logical slot p ^ (r&7).  LDS dest stays linear (global_load_lds
// writes wave-base + lane*16); the source address carries the permutation.
template<int ROWS>
__device__ __forceinline__ void stage_tile64(const bf16* __restrict__ src, int lda,
                                             bf16* tile, int tid) {
#pragma unroll
    for (int it = 0; it < ROWS / 32; ++it) {     // 256 threads cover 32 rows/iter
        int idx = it * 256 + tid;
        int row = idx >> 3;                       // 8 slots of 16B per 128B row
        int col = ((idx & 7) ^ (row & 7)) * 8;
        bf16* wavebase = tile + (idx & ~63) * 8;  // wave-uniform base
        gload_lds16(src + (size_t)row * lda + col, wavebase);
    }
}

// Fragment read with the matching XOR: logical slot s of row r lives at
// physical slot s ^ (r&7).  16 lanes (rows r..r+15) spread over 8 slots -> 2-way.
__device__ __forceinline__ bf16x8 frd64(const bf16* tile, int row, int s) {
    int p = s ^ (row & 7);
    return *(const bf16x8*)(tile + row * 64 + p * 8);
}

// ---------------- fused prep: pool + weight transforms ----------------
// Weight interleave as LDS-staged transpose: coalesced read AND write.
// Wdst[n][bin*512+d] = Wsrc[n][d*NB_+bin]
template<int NB_, int KT>
__device__ __forceinline__ void w_row_body(const float* __restrict__ Wsrc,
                                           bf16* __restrict__ Wdst,
                                           float* ld, int n, int tid) {
    const float* src = Wsrc + (size_t)n * KT;
    for (int i = tid; i < KT; i += 256) ld[i] = src[i];
    __syncthreads();
    bf16* dst = Wdst + (size_t)n * KT;
    for (int i = tid; i < KT; i += 256) {
        int bin = i >> 9, d = i & 511;
        dst[i] = (bf16)ld[d * NB_ + bin];
    }
}

__device__ __forceinline__ void pool_body(const float* __restrict__ feats,
                                          const float* __restrict__ rois,
                                          bf16* __restrict__ Xp, int m, int tid) {
    int b = m >> 10;
    float s = rois[2 * m];
    float e = rois[2 * m + 1];
    float ext = 0.2f * (e - s);
    int d0 = tid * 2;
    bf16* orow = Xp + (size_t)m * LDXP + d0;
    const float* fb = feats + (size_t)b * TT * DD + d0;
#pragma unroll
    for (int j = 0; j < NBINS; ++j) {
        float pos;
        if (j < 2)       pos = (s - ext) + ((float)j + 0.5f) * ext;
        else if (j < 11) pos = s + (((float)(j - 2) + 0.5f) * (1.0f / 9.0f)) * (e - s);
        else             pos = (e - ext) + ((float)(j - 11) + 0.5f) * ext;
        pos = fminf(fmaxf(pos, 0.0f), (float)(TT - 1));
        float fl = floorf(pos);
        int lo = (int)fl;
        int hi = lo + 1; if (hi > TT - 1) hi = TT - 1;
        float w = pos - fl;
        float2 vlo = *(const float2*)(fb + (size_t)lo * DD);
        float2 vhi = *(const float2*)(fb + (size_t)hi * DD);
        bf16x2 o;
        o.x = (bf16)((1.0f - w) * vlo.x + w * vhi.x);
        o.y = (bf16)((1.0f - w) * vlo.y + w * vhi.y);
        *(bf16x2*)(orow + j * DD) = o;
    }
}

// blocks 0..4095: pool | 4096..4607: Wl rows | 4608..5119: Wi rows | 5120..5631: Wr
__global__ __launch_bounds__(256) void prep_all(
    const float* __restrict__ feats, const float* __restrict__ rois,
    const float* __restrict__ W_left, const float* __restrict__ W_inner,
    const float* __restrict__ W_roi,
    bf16* __restrict__ Xp, bf16* __restrict__ Wl, bf16* __restrict__ Wi,
    bf16* __restrict__ Wr)
{
    __shared__ float ld[4608];
    int bid = blockIdx.x, tid = threadIdx.x;
    if (bid < 4096) {
        pool_body(feats, rois, Xp, bid, tid);
    } else if (bid < 4608) {
        w_row_body<7, 3584>(W_left, Wl, ld, bid - 4096, tid);
    } else if (bid < 5120) {
        w_row_body<9, 4608>(W_inner, Wi, ld, bid - 4608, tid);
    } else {
        int i0 = (bid - 5120) * 1024 + tid * 4;
        float4 v = *(const float4*)(W_roi + i0);
        bf16* d = Wr + i0;
        d[0] = (bf16)v.x; d[1] = (bf16)v.y; d[2] = (bf16)v.z; d[3] = (bf16)v.w;
    }
}

// ---------------- GEMM bodies ----------------
// BM=64, BN=128, BK=64; 256 threads = 4 waves (2x2), wave tile 32x64 (2x4 frags).
// Depth-2 pipeline with TWO buffers: per step, read ALL fragments to registers,
// lgkmcnt(0)+barrier (reads done), then overwrite the SAME buffer with tile t+2
// (write-after-read legal past the barrier), then pure-reg MFMA cluster.
// vmcnt wait at step t targets loads issued during step t-2 (~2 steps cover);
// never drains to 0 in the main loop.

template<int K, bool OUT_BF16>
__device__ __forceinline__ void gemm_single_body(
    const bf16* __restrict__ A, int lda,
    const bf16* __restrict__ Bw, const float* __restrict__ bias,
    void* __restrict__ Out, int ldo, int ocol0,
    bf16* sm, int m0, int n0)
{
    int tid = threadIdx.x, lane = tid & 63, w = tid >> 6;
    int wr = w >> 1, wc = w & 1;
    const bf16* Ab = A + (size_t)m0 * lda;
    const bf16* Bb = Bw + (size_t)n0 * K;
    int frow = lane & 15, sl = lane >> 4;
    f32x4 acc[2][4] = {};
    bf16 *A0 = sm,         *B0 = sm + 4096;
    bf16 *A1 = sm + 12288, *B1 = sm + 12288 + 4096;

    auto stage = [&](bf16* as, bf16* bs, int t) {   // 6 loads/thread
        stage_tile64<64>(Ab + t * 64, lda, as, tid);
        stage_tile64<128>(Bb + t * 64, K, bs, tid);
    };
    auto step_body = [&](bf16* as, bf16* bs, int t, bool dostage) {
        __builtin_amdgcn_s_barrier();              // all waves' tile-t loads done
        bf16x8 af[2][2], bfr[2][4];
#pragma unroll
        for (int ks = 0; ks < 2; ++ks) {
#pragma unroll
            for (int mf = 0; mf < 2; ++mf) af[ks][mf] = frd64(as, wr * 32 + mf * 16 + frow, ks * 4 + sl);
#pragma unroll
            for (int nf = 0; nf < 4; ++nf) bfr[ks][nf] = frd64(bs, wc * 64 + nf * 16 + frow, ks * 4 + sl);
        }
        asm volatile("s_waitcnt lgkmcnt(0)" ::: "memory");
        __builtin_amdgcn_sched_barrier(0);
        __builtin_amdgcn_s_barrier();              // all waves done reading buf
        if (dostage) stage(as, bs, t + 2);         // overwrite buf with tile t+2
        __builtin_amdgcn_s_setprio(1);
#pragma unroll
        for (int ks = 0; ks < 2; ++ks)
#pragma unroll
            for (int mf = 0; mf < 2; ++mf)
#pragma unroll
                for (int nf = 0; nf < 4; ++nf)
                    acc[mf][nf] = __builtin_amdgcn_mfma_f32_16x16x32_bf16(af[ks][mf], bfr[ks][nf], acc[mf][nf], 0, 0, 0);
        __builtin_amdgcn_s_setprio(0);
    };

    constexpr int NT = K / 64;   // even, >= 4 for all instantiations
    stage(A0, B0, 0);
    stage(A1, B1, 1);
    for (int t = 0; t + 2 < NT; t += 2) {
        wait_vm<6>(); step_body(A0, B0, t, true);
        wait_vm<6>(); step_body(A1, B1, t + 1, true);
    }
    wait_vm<6>(); step_body(A0, B0, NT - 2, false);
    wait_vm<0>(); step_body(A1, B1, NT - 1, false);

    int crow = (lane >> 4) * 4;
    int ccol = lane & 15;
#pragma unroll
    for (int mf = 0; mf < 2; ++mf) {
#pragma unroll
        for (int nf = 0; nf < 4; ++nf) {
            int col = n0 + wc * 64 + nf * 16 + ccol;
            float bv = bias[col];
#pragma unroll
            for (int r2 = 0; r2 < 4; ++r2) {
                int row = m0 + wr * 32 + mf * 16 + crow + r2;
                float v = selu_f(acc[mf][nf][r2] + bv);
                if constexpr (OUT_BF16)
                    ((bf16*)Out)[(size_t)row * ldo + ocol0 + col] = (bf16)v;
                else
                    ((float*)Out)[(size_t)row * ldo + ocol0 + col] = v;
            }
        }
    }
}

template<int K>
__device__ __forceinline__ void gemm_dual_body(
    const bf16* __restrict__ Xp, const bf16* __restrict__ Wl,
    const float* __restrict__ bias, bf16* __restrict__ Y,
    bf16* sm, int m0, int n0)
{
    int tid = threadIdx.x, lane = tid & 63, w = tid >> 6;
    int wr = w >> 1, wc = w & 1;
    const bf16* AL = Xp + (size_t)m0 * LDXP;         // bins 0..6
    const bf16* AR = AL + 3072;                      // bins 6..12
    const bf16* Bb = Wl + (size_t)n0 * K;
    int frow = lane & 15, sl = lane >> 4;
    f32x4 accL[2][4] = {}, accR[2][4] = {};
    bf16 *L0 = sm,         *R0 = sm + 4096,         *B0 = sm + 8192;
    bf16 *L1 = sm + 16384, *R1 = sm + 16384 + 4096, *B1 = sm + 16384 + 8192;

    auto stage = [&](bf16* ls, bf16* rs, bf16* bs, int t) {  // 8 loads/thread
        stage_tile64<64>(AL + t * 64, LDXP, ls, tid);
        stage_tile64<64>(AR + t * 64, LDXP, rs, tid);
        stage_tile64<128>(Bb + t * 64, K, bs, tid);
    };
    auto step_body = [&](bf16* ls, bf16* rs, bf16* bs, int t, bool dostage) {
        __builtin_amdgcn_s_barrier();
        bf16x8 afL[2][2], afR[2][2], bfr[2][4];
#pragma unroll
        for (int ks = 0; ks < 2; ++ks) {
#pragma unroll
            for (int mf = 0; mf < 2; ++mf) {
                afL[ks][mf] = frd64(ls, wr * 32 + mf * 16 + frow, ks * 4 + sl);
                afR[ks][mf] = frd64(rs, wr * 32 + mf * 16 + frow, ks * 4 + sl);
            }
#pragma unroll
            for (int nf = 0; nf < 4; ++nf) bfr[ks][nf] = frd64(bs, wc * 64 + nf * 16 + frow, ks * 4 + sl);
        }
        asm volatile("s_waitcnt lgkmcnt(0)" ::: "memory");
        __builtin_amdgcn_sched_barrier(0);
        __builtin_amdgcn_s_barrier();
        if (dostage) stage(ls, rs, bs, t + 2);
        __builtin_amdgcn_s_setprio(1);
#pragma unroll
        for (int ks = 0; ks < 2; ++ks)
#pragma unroll
            for (int mf = 0; mf < 2; ++mf)
#pragma unroll
                for (int nf = 0; nf < 4; ++nf) {
                    accL[mf][nf] = __builtin_amdgcn_mfma_f32_16x16x32_bf16(afL[ks][mf], bfr[ks][nf], accL[mf][nf], 0, 0, 0);
                    accR[mf][nf] = __builtin_amdgcn_mfma_f32_16x16x32_bf16(afR[ks][mf], bfr[ks][nf], accR[mf][nf], 0, 0, 0);
                }
        __builtin_amdgcn_s_setprio(0);
    };

    constexpr int NT = K / 64;   // 56
    stage(L0, R0, B0, 0);
    stage(L1, R1, B1, 1);
    for (int t = 0; t + 2 < NT; t += 2) {
        wait_vm<8>(); step_body(L0, R0, B0, t, true);
        wait_vm<8>(); step_body(L1, R1, B1, t + 1, true);
    }
    wait_vm<8>(); step_body(L0, R0, B0, NT - 2, false);
    wait_vm<0>(); step_body(L1, R1, B1, NT - 1, false);

    int crow = (lane >> 4) * 4;
    int ccol = lane & 15;
#pragma unroll
    for (int mf = 0; mf < 2; ++mf) {
#pragma unroll
        for (int nf = 0; nf < 4; ++nf) {
            int col = n0 + wc * 64 + nf * 16 + ccol;
            float bv = bias[col];
#pragma unroll
            for (int r2 = 0; r2 < 4; ++r2) {
                int row = m0 + wr * 32 + mf * 16 + crow + r2;
                float vL = selu_f(accL[mf][nf][r2] + bv);
                float vR = selu_f(accR[mf][nf][r2] + bv);
                Y[(size_t)row * 1024 + col] = (bf16)(vR - vL);
            }
        }
    }
}

// ---------------- GEMM kernels ----------------
// Linear mapping (measured best): dual bids 0..255 (m-major), inner 256..511.
// bid and bid+64 share an XCD, so all 4 n-strips of an m-tile co-locate and
// all 64 blocks of an XCD are co-resident -> weights fetched ~once per XCD.
__global__ __launch_bounds__(256) void wide_gemm(
    const bf16* __restrict__ Xp, const bf16* __restrict__ Wl,
    const float* __restrict__ bl, const bf16* __restrict__ Wi,
    const float* __restrict__ bi, bf16* __restrict__ Y)
{
    __shared__ bf16 sm[32768];  // 64 KB: 2 x (64+64+128)x64
    int bid = blockIdx.x;
    if (bid < 256) {
        gemm_dual_body<3584>(Xp, Wl, bl, Y, sm, (bid & 63) * 64, (bid >> 6) * 128);
    } else {
        int b2 = bid - 256;
        gemm_single_body<4608, true>(Xp + 1024, LDXP, Wi, bi, (void*)Y, 1024, 512,
                                     sm, (b2 & 63) * 64, (b2 >> 6) * 128);
    }
}

__global__ __launch_bounds__(256) void final_gemm(
    const bf16* __restrict__ Y, const bf16* __restrict__ Wr,
    const float* __restrict__ br, float* __restrict__ out)
{
    __shared__ bf16 sm[24576];  // 48 KB
    int bid = blockIdx.x;
    gemm_single_body<1024, false>(Y, 1024, Wr, br, (void*)out, 512, 0,
                                  sm, (bid & 63) * 64, (bid >> 6) * 128);
}

// ---------------- launch ----------------
extern "C" void kernel_launch(void* const* d_in, const int* in_sizes, int n_in,
                              void* d_out, int out_size, void* d_ws, size_t ws_size,
                              hipStream_t stream) {
    const float* feats   = (const float*)d_in[0];
    const float* rois    = (const float*)d_in[3];
    const float* W_left  = (const float*)d_in[6];
    const float* b_left  = (const float*)d_in[7];
    const float* W_inner = (const float*)d_in[8];
    const float* b_inner = (const float*)d_in[9];
    const float* W_roi   = (const float*)d_in[10];
    const float* b_roi   = (const float*)d_in[11];
    float* out = (float*)d_out;

    bf16* wsb = (bf16*)d_ws;
    constexpr size_t XP_ELEMS = (size_t)MM * LDXP;
    constexpr size_t WL_ELEMS = (size_t)512 * 3584;
    constexpr size_t WI_ELEMS = (size_t)512 * 4608;
    constexpr size_t WR_ELEMS = (size_t)512 * 1024;
    bf16* Xp = wsb;
    bf16* Wl = Xp + XP_ELEMS;
    bf16* Wi = Wl + WL_ELEMS;
    bf16* Wr = Wi + WI_ELEMS;
    bf16* Y  = Wr + WR_ELEMS;   // [M][1024]

    prep_all<<<5632, 256, 0, stream>>>(feats, rois, W_left, W_inner, W_roi,
                                       Xp, Wl, Wi, Wr);
    wide_gemm<<<512, 256, 0, stream>>>(Xp, Wl, b_left, Wi, b_inner, Y);
    final_gemm<<<256, 256, 0, stream>>>(Y, Wr, b_roi, out);
}